// Round 1
// baseline (134.503 us; speedup 1.0000x reference)
//
#include <hip/hip_runtime.h>
#include <math.h>

#define TWO_PI_F 6.28318530717958647692f
#define BN_EPS_F 1e-5f

// ---------------------------------------------------------------------------
// Workspace layout (as float*/unsigned* on d_ws):
//   wsu[0] : min key (monotone uint encoding of float)
//   wsu[1] : max key
//   wsf[2..9]  : BN stats accumulators (sum0..3, sumsq0..3)
//   wsf[16..63]: gate table: [l][i][4] = {ry_c, ry_s, rz_c, rz_s}
// ---------------------------------------------------------------------------

__device__ __forceinline__ unsigned f2key(float f) {
  unsigned u = __float_as_uint(f);
  return (u & 0x80000000u) ? ~u : (u | 0x80000000u);
}
__device__ __forceinline__ float key2f(unsigned k) {
  unsigned u = (k & 0x80000000u) ? (k ^ 0x80000000u) : ~k;
  return __uint_as_float(u);
}

// K0: init accumulators + precompute weight gates (runs fully every call;
// ws is re-poisoned before every timed launch).
__global__ void k_init(const float* __restrict__ w, float* __restrict__ wsf) {
  if (threadIdx.x == 0) {
    unsigned* wsu = (unsigned*)wsf;
    wsu[0] = 0xFFFFFFFFu;  // min-key slot: largest key
    wsu[1] = 0x00000000u;  // max-key slot: smallest key
    for (int j = 0; j < 8; ++j) wsf[2 + j] = 0.0f;
    for (int l = 0; l < 3; ++l) {
      for (int i = 0; i < 4; ++i) {
        float th_ry = w[(l * 4 + i) * 2 + 0];
        float th_rz = w[(l * 4 + i) * 2 + 1];
        wsf[16 + l * 16 + i * 4 + 0] = cosf(0.5f * th_ry);
        wsf[16 + l * 16 + i * 4 + 1] = sinf(0.5f * th_ry);
        wsf[16 + l * 16 + i * 4 + 2] = cosf(0.5f * th_rz);
        wsf[16 + l * 16 + i * 4 + 3] = sinf(0.5f * th_rz);
      }
    }
  }
}

// K1: global min/max over x[:, 0:4] of the [B,16] input.
__global__ __launch_bounds__(256) void k_minmax(const float* __restrict__ x,
                                                unsigned* __restrict__ wsu, int B) {
  float fmn = __builtin_inff();
  float fmx = -__builtin_inff();
  for (int r = blockIdx.x * blockDim.x + threadIdx.x; r < B;
       r += gridDim.x * blockDim.x) {
    float4 v = *(const float4*)(x + (size_t)r * 16);
    fmn = fminf(fmn, fminf(fminf(v.x, v.y), fminf(v.z, v.w)));
    fmx = fmaxf(fmx, fmaxf(fmaxf(v.x, v.y), fmaxf(v.z, v.w)));
  }
#pragma unroll
  for (int d = 32; d; d >>= 1) {
    fmn = fminf(fmn, __shfl_down(fmn, d));
    fmx = fmaxf(fmx, __shfl_down(fmx, d));
  }
  __shared__ float smn[4], smx[4];
  int wave = threadIdx.x >> 6, lane = threadIdx.x & 63;
  if (lane == 0) { smn[wave] = fmn; smx[wave] = fmx; }
  __syncthreads();
  if (threadIdx.x == 0) {
    float bmn = fminf(fminf(smn[0], smn[1]), fminf(smn[2], smn[3]));
    float bmx = fmaxf(fmaxf(smx[0], smx[1]), fmaxf(smx[2], smx[3]));
    atomicMin(&wsu[0], f2key(bmn));
    atomicMax(&wsu[1], f2key(bmx));
  }
}

// K2: per-sample circuit simulation + linear; write pre-BN out; accumulate stats.
__global__ __launch_bounds__(256) void k_main(const float* __restrict__ x,
                                              const float* __restrict__ wsf,
                                              const float* __restrict__ fc_w,
                                              const float* __restrict__ fc_b,
                                              float* __restrict__ out, int B) {
  int b = blockIdx.x * 256 + threadIdx.x;
  const unsigned* wsu = (const unsigned*)wsf;
  float mn = key2f(wsu[0]);
  float mx = key2f(wsu[1]);
  float denom = mx - mn + 1e-8f;

  float o[4] = {0.f, 0.f, 0.f, 0.f};
  if (b < B) {
    float4 xv = *(const float4*)(x + (size_t)b * 16);
    float ang[4] = {TWO_PI_F * (xv.x - mn) / denom, TWO_PI_F * (xv.y - mn) / denom,
                    TWO_PI_F * (xv.z - mn) / denom, TWO_PI_F * (xv.w - mn) / denom};
    float cq[4], sq[4];
#pragma unroll
    for (int i = 0; i < 4; ++i) __sincosf(0.5f * ang[i], &sq[i], &cq[i]);

    // encoded product state (real)
    float sr[16], si[16];
#pragma unroll
    for (int k = 0; k < 16; ++k) {
      sr[k] = ((k & 8) ? sq[0] : cq[0]) * ((k & 4) ? sq[1] : cq[1]) *
              ((k & 2) ? sq[2] : cq[2]) * ((k & 1) ? sq[3] : cq[3]);
      si[k] = 0.f;
    }

    const float* gt = wsf + 16;
#pragma unroll
    for (int l = 0; l < 3; ++l) {
#pragma unroll
      for (int i = 0; i < 4; ++i) {
        const int m = 8 >> i;
        float ryc = gt[l * 16 + i * 4 + 0];
        float rys = gt[l * 16 + i * 4 + 1];
        float rzc = gt[l * 16 + i * 4 + 2];
        float rzs = gt[l * 16 + i * 4 + 3];
        // RY (real 2x2) on qubit i
#pragma unroll
        for (int k = 0; k < 16; ++k) {
          if (!(k & m)) {
            int k1 = k | m;
            float a0r = sr[k], a0i = si[k], a1r = sr[k1], a1i = si[k1];
            sr[k]  = ryc * a0r - rys * a1r;
            si[k]  = ryc * a0i - rys * a1i;
            sr[k1] = rys * a0r + ryc * a1r;
            si[k1] = rys * a0i + ryc * a1i;
          }
        }
        // RZ (diag phase) on qubit i: bit0 -> e^{-i th/2}, bit1 -> e^{+i th/2}
#pragma unroll
        for (int k = 0; k < 16; ++k) {
          float ps = (k & m) ? rzs : -rzs;
          float r = sr[k], ii = si[k];
          sr[k] = r * rzc - ii * ps;
          si[k] = r * ps + ii * rzc;
        }
      }
      // CNOT ring: (0,1),(1,2),(2,3),(3,0)
#pragma unroll
      for (int c = 0; c < 4; ++c) {
        const int mc = 8 >> c;
        const int mt = 8 >> ((c + 1) & 3);
#pragma unroll
        for (int k = 0; k < 16; ++k) {
          if ((k & mc) && !(k & mt)) {
            int k2 = k | mt;
            float t;
            t = sr[k]; sr[k] = sr[k2]; sr[k2] = t;
            t = si[k]; si[k] = si[k2]; si[k2] = t;
          }
        }
      }
    }

    // PauliZ expvals per qubit
    float z[4] = {0.f, 0.f, 0.f, 0.f};
#pragma unroll
    for (int k = 0; k < 16; ++k) {
      float p = sr[k] * sr[k] + si[k] * si[k];
#pragma unroll
      for (int i = 0; i < 4; ++i) z[i] += (k & (8 >> i)) ? -p : p;
    }
    // Linear(4,4)
#pragma unroll
    for (int j = 0; j < 4; ++j) {
      float acc = fc_b[j];
#pragma unroll
      for (int i = 0; i < 4; ++i) acc += fc_w[j * 4 + i] * z[i];
      o[j] = acc;
    }
    *(float4*)(out + (size_t)b * 4) = make_float4(o[0], o[1], o[2], o[3]);
  }

  // BN stats: block reduce 8 values, one atomicAdd set per block
  float vals[8] = {o[0], o[1], o[2], o[3],
                   o[0] * o[0], o[1] * o[1], o[2] * o[2], o[3] * o[3]};
#pragma unroll
  for (int j = 0; j < 8; ++j) {
#pragma unroll
    for (int d = 32; d; d >>= 1) vals[j] += __shfl_down(vals[j], d);
  }
  __shared__ float red[4][8];
  int wave = threadIdx.x >> 6, lane = threadIdx.x & 63;
  if (lane == 0) {
#pragma unroll
    for (int j = 0; j < 8; ++j) red[wave][j] = vals[j];
  }
  __syncthreads();
  if (threadIdx.x < 8) {
    float s = red[0][threadIdx.x] + red[1][threadIdx.x] + red[2][threadIdx.x] +
              red[3][threadIdx.x];
    float* stats = (float*)wsf + 2;
    atomicAdd(&stats[threadIdx.x], s);
  }
}

// K3: in-place BatchNorm finalize on d_out.
__global__ __launch_bounds__(256) void k_final(float* __restrict__ out,
                                               const float* __restrict__ wsf,
                                               const float* __restrict__ gamma,
                                               const float* __restrict__ beta, int B) {
  int b = blockIdx.x * 256 + threadIdx.x;
  if (b >= B) return;
  const float* stats = wsf + 2;
  float inv = 1.0f / (float)B;
  float4 v = *(float4*)(out + (size_t)b * 4);
  float vv[4] = {v.x, v.y, v.z, v.w};
  float res[4];
#pragma unroll
  for (int j = 0; j < 4; ++j) {
    float mean = stats[j] * inv;
    float var = stats[4 + j] * inv - mean * mean;
    res[j] = gamma[j] * (vv[j] - mean) * rsqrtf(var + BN_EPS_F) + beta[j];
  }
  *(float4*)(out + (size_t)b * 4) = make_float4(res[0], res[1], res[2], res[3]);
}

extern "C" void kernel_launch(void* const* d_in, const int* in_sizes, int n_in,
                              void* d_out, int out_size, void* d_ws, size_t ws_size,
                              hipStream_t stream) {
  const float* x     = (const float*)d_in[0];
  const float* w     = (const float*)d_in[1];
  const float* fc_w  = (const float*)d_in[2];
  const float* fc_b  = (const float*)d_in[3];
  const float* gamma = (const float*)d_in[4];
  const float* beta  = (const float*)d_in[5];
  float* out = (float*)d_out;
  float* wsf = (float*)d_ws;
  unsigned* wsu = (unsigned*)d_ws;
  int B = in_sizes[0] / 16;

  k_init<<<1, 64, 0, stream>>>(w, wsf);
  k_minmax<<<512, 256, 0, stream>>>(x, wsu, B);
  k_main<<<(B + 255) / 256, 256, 0, stream>>>(x, wsf, fc_w, fc_b, out, B);
  k_final<<<(B + 255) / 256, 256, 0, stream>>>(out, wsf, gamma, beta, B);
}